// Round 22
// baseline (112.606 us; speedup 1.0000x reference)
//
#include <hip/hip_runtime.h>

#define N 8192
#define D 512

typedef __attribute__((ext_vector_type(4))) float f32x4;
typedef __attribute__((ext_vector_type(2))) long long2v;

typedef const __attribute__((address_space(1))) unsigned int* gas_t;
typedef __attribute__((address_space(3))) unsigned int* las_t;

static __device__ __forceinline__ void gl_lds16(const void* g, char* l) {
    __builtin_amdgcn_global_load_lds((gas_t)g, (las_t)l, 16, 0, 0);
}
// triangle cumulative for the 64x64 grid of 128-wide tiles: row r owns (64-r) tiles
static __device__ __forceinline__ int tri_cum(int r) { return r * (129 - r) / 2; }

// OCP e4m3 encode (RNE, saturate 448; our inputs are <=~0.7 so never saturate)
static __device__ __forceinline__ unsigned f2fp8(float f) {
    unsigned u = __float_as_uint(f);
    unsigned sgn = (u >> 24) & 0x80u;
    unsigned a = u & 0x7FFFFFFFu;
    if (a >= 0x3C800000u) {                               // >= 2^-6: normal
        unsigned t = a + 0x7FFFFu + ((a >> 20) & 1u);     // RNE to 3-bit mantissa
        unsigned code = (((t >> 23) - 120u) << 3) | ((t >> 20) & 7u);
        if (code > 0x7Eu) code = 0x7Eu;                   // clamp to 448
        return sgn | code;
    }
    float af = __uint_as_float(a);
    unsigned m = (unsigned)(af * 512.0f + 0.5f);          // subnormal: m * 2^-9
    return sgn | (m > 8u ? 8u : m);                       // m==8 -> min normal
}
// OCP e4m3 decode (exact)
static __device__ __forceinline__ float fp82f(unsigned c) {
    unsigned e = (c >> 3) & 15u, m = c & 7u;
    float v = (e == 0u) ? (float)m * 0.001953125f
                        : __uint_as_float(((e + 120u) << 23) | (m << 20));
    return (c & 0x80u) ? -v : v;
}

// K1 (runs FIRST): row-normalize embeddings -> fp8 e4m3 e[N][D], PRE-SCALED by
// sqrt(10*log2(e)); 64B K-chunks stored with 8B units permuted [0,4,1,5,2,6,3,7]
// (one 16B granule = both K-half fragments -> conflict-free b128 in kmain).
// Also inits srow/jminrow/negrow for its 4 rows and zeroes d2mb.
__global__ void knorm(const float* __restrict__ emb, unsigned char* __restrict__ e,
                      float* __restrict__ srow, unsigned* __restrict__ jminrow,
                      unsigned* __restrict__ negrow, unsigned* __restrict__ d2mb) {
    int w    = threadIdx.x >> 6;
    int row  = blockIdx.x * 4 + w;
    int lane = threadIdx.x & 63;
    const float4* src = (const float4*)(emb + (size_t)row * D);
    float4 v0 = src[lane * 2];
    float4 v1 = src[lane * 2 + 1];
    float ss = v0.x*v0.x + v0.y*v0.y + v0.z*v0.z + v0.w*v0.w
             + v1.x*v1.x + v1.y*v1.y + v1.z*v1.z + v1.w*v1.w;
#pragma unroll
    for (int off = 1; off < 64; off <<= 1) ss += __shfl_xor(ss, off, 64);
    // 3.7982826^2 = 14.42695 = 10*log2(e): acc becomes exp2 argument directly
    float inv = 3.7982826f / fmaxf(sqrtf(ss), 1e-12f);
    unsigned c0 = f2fp8(v0.x * inv), c1 = f2fp8(v0.y * inv);
    unsigned c2 = f2fp8(v0.z * inv), c3 = f2fp8(v0.w * inv);
    unsigned c4 = f2fp8(v1.x * inv), c5 = f2fp8(v1.y * inv);
    unsigned c6 = f2fp8(v1.z * inv), c7 = f2fp8(v1.w * inv);
    uint2 pk;
    pk.x = c0 | (c1 << 8) | (c2 << 16) | (c3 << 24);
    pk.y = c4 | (c5 << 8) | (c6 << 16) | (c7 << 24);
    {   // permuted store: lane covers K [lane*8, lane*8+8) = chunk c, unit u
        int c = lane >> 3, u = lane & 7;
        int off8 = c * 64 + ((u < 4) ? u * 16 : (u - 4) * 16 + 8);
        *(uint2*)(e + (size_t)row * D + off8) = pk;
    }
    if (lane == 0) {
        srow[row] = 0.0f;
        jminrow[row] = 0xFFFFFFFFu;
        negrow[row] = 0u;
    }
    if (blockIdx.x == 0 && threadIdx.x == 0) *d2mb = 0u;
}

// K2: pack thetas -> float4 (x,y,z,|t|^2) AND global theta-d2max from RAW th
// (no dependency on th4; d2mb zeroed by knorm which runs first).
__global__ void kth(const float* __restrict__ th, float4* __restrict__ th4,
                    unsigned* __restrict__ d2mb) {
    int tid = threadIdx.x, bid = blockIdx.x;
    if (bid < 32) {
        int i = bid * 256 + tid;
        float x = th[3 * i], y = th[3 * i + 1], z = th[3 * i + 2];
        float4 v; v.x = x; v.y = y; v.z = z; v.w = x * x + y * y + z * z;
        th4[i] = v;
    }
    int w = tid >> 6, lane = tid & 63;
    int widx = bid * 4 + w;             // 0..1023
    int q0 = widx * 4;
    int m0 = N - 4 - q0;
    float4 A[4], B[4];
#pragma unroll
    for (int k = 0; k < 4; k++) {
        float x = th[3 * (q0 + k)], y = th[3 * (q0 + k) + 1], z = th[3 * (q0 + k) + 2];
        A[k].x = x; A[k].y = y; A[k].z = z; A[k].w = x * x + y * y + z * z;
        x = th[3 * (m0 + k)]; y = th[3 * (m0 + k) + 1]; z = th[3 * (m0 + k) + 2];
        B[k].x = x; B[k].y = y; B[k].z = z; B[k].w = x * x + y * y + z * z;
    }
    float m = 0.0f;
    for (int j = q0 + 1 + lane; j < N; j += 64) {
        float x = th[3 * j], y = th[3 * j + 1], z = th[3 * j + 2];
        float tw = x * x + y * y + z * z;
        float d;
        d = A[0].w + tw - 2.0f * (A[0].x*x + A[0].y*y + A[0].z*z); m = fmaxf(m, d);
        d = A[1].w + tw - 2.0f * (A[1].x*x + A[1].y*y + A[1].z*z); m = fmaxf(m, d);
        d = A[2].w + tw - 2.0f * (A[2].x*x + A[2].y*y + A[2].z*z); m = fmaxf(m, d);
        d = A[3].w + tw - 2.0f * (A[3].x*x + A[3].y*y + A[3].z*z); m = fmaxf(m, d);
    }
    for (int j = m0 + 1 + lane; j < N; j += 64) {
        float x = th[3 * j], y = th[3 * j + 1], z = th[3 * j + 2];
        float tw = x * x + y * y + z * z;
        float d;
        d = B[0].w + tw - 2.0f * (B[0].x*x + B[0].y*y + B[0].z*z); m = fmaxf(m, d);
        d = B[1].w + tw - 2.0f * (B[1].x*x + B[1].y*y + B[1].z*z); m = fmaxf(m, d);
        d = B[2].w + tw - 2.0f * (B[2].x*x + B[2].y*y + B[2].z*z); m = fmaxf(m, d);
        d = B[3].w + tw - 2.0f * (B[3].x*x + B[3].y*y + B[3].z*z); m = fmaxf(m, d);
    }
#pragma unroll
    for (int off = 1; off < 64; off <<= 1) m = fmaxf(m, __shfl_xor(m, off, 64));
    __shared__ float red[4];
    if (lane == 0) red[w] = m;
    __syncthreads();
    if (tid == 0) {
        m = fmaxf(fmaxf(red[0], red[1]), fmaxf(red[2], red[3]));
        atomicMax(d2mb, __float_as_uint(m));
    }
}

// K4: symmetric fused GEMM, fp8 e4m3, 128x128 tile over the 64x64 triangle grid
// (2080 blocks), 256 threads = 4 waves (2Mx2N, 64x64/wave, acc 4x4). BK=64,
// THREE 16KB tile-buffers (48 KB LDS), counted vmcnt(4) ring. Conflict-free b128
// fragments (unit-permuted layout). NEW vs r21: T5 s_setprio(1) around the MFMA
// cluster — favors MFMA-feeding waves over co-resident blocks' epilogue-VALU waves.
__global__ __launch_bounds__(256) void kmain(
    const unsigned char* __restrict__ e, const float4* __restrict__ th4,
    const unsigned* __restrict__ d2mb, float* __restrict__ srow,
    unsigned* __restrict__ jminrow, unsigned* __restrict__ negrow) {
    __shared__ __align__(16) char smem[49152];   // 3 bufs x (A 8K + B 8K)

    const int tid  = threadIdx.x;
    const int lane = tid & 63;
    const int w    = tid >> 6;        // 0..3
    const int wr   = w >> 1;          // 0..1 (M 64-half)
    const int wc   = w & 1;           // 0..1 (N 64-half)

    // XCD-aware bijective swizzle: 2080 = 8 XCDs x 260; triangle decode (64 rows)
    const int bid = (int)blockIdx.x;
    const int swz = (bid & 7) * 260 + (bid >> 3);
    int rb = (int)((129.0f - sqrtf(16641.0f - 8.0f * (float)swz)) * 0.5f);
    rb = rb < 0 ? 0 : (rb > 63 ? 63 : rb);
    while (tri_cum(rb + 1) <= swz) rb++;
    while (tri_cum(rb) > swz) rb--;
    const int cb = rb + (swz - tri_cum(rb));
    const bool isdiag = (rb == cb);
    const int r0 = rb * 128, c0 = cb * 128;

    // staging (BK=64 fp8): per buf, A = 128 rows x 64 B at [0], B at [8192].
    // thread t pass p: row = (t>>2) + 64p, 16B-granule = t&3; LDS dest linear
    // t*16 (+4096/pass). global granule pre-swizzled:
    // LDS[row][g] = global(row, g ^ ((row>>1)&3)).
    const int ssw = (((tid & 3) ^ ((tid >> 3) & 3)) << 4);   // byte offset
    const unsigned char* pA0 = e + (size_t)(r0 + (tid >> 2)) * D + ssw;
    const unsigned char* pA1 = pA0 + (size_t)64 * D;
    const unsigned char* pB0 = e + (size_t)(c0 + (tid >> 2)) * D + ssw;
    const unsigned char* pB1 = pB0 + (size_t)64 * D;

    const int fr = lane & 15;
    const int fq = lane >> 4;
    // one b128 per fragment: granule fq ^ ((fr>>1)&3); contains both ks halves
    const int kslot = (fq ^ ((fr >> 1) & 3)) << 4;

    f32x4 acc[4][4];
#pragma unroll
    for (int mt = 0; mt < 4; mt++)
#pragma unroll
        for (int nt = 0; nt < 4; nt++) acc[mt][nt] = (f32x4){0.f, 0.f, 0.f, 0.f};

#define STAGE(T, BUF) { \
    const int k0_ = (T) * 64; char* d_ = smem + (BUF) * 16384;   \
    gl_lds16(pA0 + k0_, d_ + tid * 16);                          \
    gl_lds16(pA1 + k0_, d_ + 4096 + tid * 16);                   \
    gl_lds16(pB0 + k0_, d_ + 8192 + tid * 16);                   \
    gl_lds16(pB1 + k0_, d_ + 12288 + tid * 16); }

#define COMPUTE(BUF) { \
    const char* cA_ = smem + (BUF) * 16384;                      \
    const char* cB_ = cA_ + 8192;                                \
    long2v a_[4], b_[4];                                         \
    _Pragma("unroll")                                            \
    for (int mt = 0; mt < 4; mt++)                               \
        a_[mt] = *(const long2v*)(cA_ + (wr * 64 + mt * 16 + fr) * 64 + kslot); \
    _Pragma("unroll")                                            \
    for (int nt = 0; nt < 4; nt++)                               \
        b_[nt] = *(const long2v*)(cB_ + (wc * 64 + nt * 16 + fr) * 64 + kslot); \
    __builtin_amdgcn_s_setprio(1);                               \
    _Pragma("unroll")                                            \
    for (int mt = 0; mt < 4; mt++)                               \
    _Pragma("unroll")                                            \
    for (int nt = 0; nt < 4; nt++) {                             \
        acc[mt][nt] = __builtin_amdgcn_mfma_f32_16x16x32_fp8_fp8( \
            a_[mt][0], b_[nt][0], acc[mt][nt], 0, 0, 0);         \
        acc[mt][nt] = __builtin_amdgcn_mfma_f32_16x16x32_fp8_fp8( \
            a_[mt][1], b_[nt][1], acc[mt][nt], 0, 0, 0);         \
    }                                                            \
    __builtin_amdgcn_s_setprio(0); }

// step: counted wait (stage T landed; T+1 in flight) -> barrier -> issue T+2 -> compute T
#define KST(WAITN, SBUF, DOSTAGE, ST, CBUF)                       \
    asm volatile("s_waitcnt vmcnt(" #WAITN ")" ::: "memory");     \
    __builtin_amdgcn_s_barrier();                                 \
    __builtin_amdgcn_sched_barrier(0);                            \
    if (DOSTAGE) STAGE(ST, SBUF)                                  \
    COMPUTE(CBUF)

    STAGE(0, 0)
    STAGE(1, 1)
    KST(4, 2, 1, 2, 0)   // T=0
    KST(4, 0, 1, 3, 1)   // T=1
    KST(4, 1, 1, 4, 2)   // T=2
    KST(4, 2, 1, 5, 0)   // T=3
    KST(4, 0, 1, 6, 1)   // T=4
    KST(4, 1, 1, 7, 2)   // T=5
    KST(4, 0, 0, 0, 0)   // T=6 (no stage)
    KST(0, 0, 0, 0, 1)   // T=7 (final drain)
#undef KST
#undef COMPUTE
#undef STAGE
    __syncthreads();   // all compute done; LDS reused by the reduction below

    // ---- fused epilogue (acc is the exp2 argument directly) ----
    const float dmax = sqrtf(__uint_as_float(*d2mb)) + 1e-8f;
    const float p2 = 0.0225f * dmax * dmax;   // (0.15*dmax)^2
    const float n2 = 0.1225f * dmax * dmax;   // (0.35*dmax)^2

    const int j0 = c0 + wc * 64 + fr;
    float4 thj[4];
#pragma unroll
    for (int nt = 0; nt < 4; nt++) thj[nt] = th4[j0 + nt * 16];

    float*    lds_rs = (float*)smem;              // [2][128] row sums (by wc)
    unsigned* lds_rj = (unsigned*)(smem + 1024);
    unsigned* lds_rn = (unsigned*)(smem + 2048);
    float*    lds_cs = (float*)(smem + 3072);     // [2][128] col sums (by wr)
    unsigned* lds_cj = (unsigned*)(smem + 4096);
    unsigned* lds_cn = (unsigned*)(smem + 5120);

    float    csum[4]; unsigned cjm[4], cng[4];
#pragma unroll
    for (int nt = 0; nt < 4; nt++) { csum[nt] = 0.0f; cjm[nt] = 0xFFFFFFFFu; cng[nt] = 0u; }

    const int i0 = r0 + wr * 64 + fq * 4;
#pragma unroll
    for (int mt = 0; mt < 4; mt++) {
#pragma unroll
        for (int rr = 0; rr < 4; rr++) {
            const int i = i0 + mt * 16 + rr;
            const float4 ti = th4[i];
            float sv = 0.0f; unsigned jv = 0xFFFFFFFFu, nv = 0u;
#pragma unroll
            for (int nt = 0; nt < 4; nt++) {
                const int j = j0 + nt * 16;
                const float4 tj = thj[nt];
                float dot = ti.x * tj.x + ti.y * tj.y + ti.z * tj.z;
                float d2 = fmaf(-2.0f, dot, ti.w + tj.w);
                bool pos = isdiag ? ((d2 < p2) && (j != i)) : (d2 < p2);
                bool neg = (d2 > n2);
                float c = (pos || neg) ? exp2f(acc[mt][nt][rr]) : 0.0f;
                sv += c;
                if (neg) nv = 1u;
                if (pos) jv = min(jv, (unsigned)j);
                if (!isdiag) {
                    csum[nt] += c;
                    if (neg) cng[nt] = 1u;
                    if (pos) cjm[nt] = min(cjm[nt], (unsigned)i);
                }
            }
            // row-side reduce across the 16 fr-lanes
#pragma unroll
            for (int off = 1; off < 16; off <<= 1) {
                sv += __shfl_xor(sv, off, 64);
                jv = min(jv, (unsigned)__shfl_xor((int)jv, off, 64));
                nv |= (unsigned)__shfl_xor((int)nv, off, 64);
            }
            if (fr == 0) {
                const int rl = wr * 64 + mt * 16 + fq * 4 + rr;
                lds_rs[wc * 128 + rl] = sv;
                lds_rj[wc * 128 + rl] = jv;
                lds_rn[wc * 128 + rl] = nv;
            }
        }
    }

    // column-side reduce across the 4 fq groups (lane^16, lane^32)
    if (!isdiag) {
#pragma unroll
        for (int nt = 0; nt < 4; nt++) {
            float sv = csum[nt]; unsigned jv = cjm[nt], nv = cng[nt];
#pragma unroll
            for (int off = 16; off < 64; off <<= 1) {
                sv += __shfl_xor(sv, off, 64);
                jv = min(jv, (unsigned)__shfl_xor((int)jv, off, 64));
                nv |= (unsigned)__shfl_xor((int)nv, off, 64);
            }
            if (fq == 0) {
                const int cl = wc * 64 + nt * 16 + fr;
                lds_cs[wr * 128 + cl] = sv;
                lds_cj[wr * 128 + cl] = jv;
                lds_cn[wr * 128 + cl] = nv;
            }
        }
    }
    __syncthreads();
    if (tid < 128) {
        float    sv = lds_rs[tid] + lds_rs[128 + tid];
        unsigned jv = min(lds_rj[tid], lds_rj[128 + tid]);
        unsigned nv = lds_rn[tid] | lds_rn[128 + tid];
        atomicAdd(&srow[r0 + tid], sv);
        atomicMin(&jminrow[r0 + tid], jv);
        atomicOr(&negrow[r0 + tid], nv);
        if (!isdiag) {
            float    cv = lds_cs[tid] + lds_cs[128 + tid];
            unsigned cj = min(lds_cj[tid], lds_cj[128 + tid]);
            unsigned cn = lds_cn[tid] | lds_cn[128 + tid];
            atomicAdd(&srow[c0 + tid], cv);
            atomicMin(&jminrow[c0 + tid], cj);
            atomicOr(&negrow[c0 + tid], cn);
        }
    }
}

// K5: per-row finalize. e is fp8 (unit-permuted rows; dot is permutation-invariant),
// pre-scaled: sim = dot_scaled * ln2.
__global__ void krow(const unsigned char* __restrict__ e, const float* __restrict__ srow,
                     const unsigned* __restrict__ jminrow, const unsigned* __restrict__ negrow,
                     float* __restrict__ pr, float* __restrict__ vf) {
    int row  = blockIdx.x * 4 + (threadIdx.x >> 6);
    int lane = threadIdx.x & 63;
    unsigned jmv = jminrow[row];
    bool valid = (jmv != 0xFFFFFFFFu) && (negrow[row] != 0u);
    float p = 0.0f;
    if (valid) {
        const uint2* a = (const uint2*)(e + (size_t)row * D);
        const uint2* b = (const uint2*)(e + (size_t)jmv * D);
        uint2 va = a[lane], vb = b[lane];
        float dot = 0.0f;
#pragma unroll
        for (int k = 0; k < 4; k++)
            dot += fp82f((va.x >> (8 * k)) & 0xFFu) * fp82f((vb.x >> (8 * k)) & 0xFFu);
#pragma unroll
        for (int k = 0; k < 4; k++)
            dot += fp82f((va.y >> (8 * k)) & 0xFFu) * fp82f((vb.y >> (8 * k)) & 0xFFu);
#pragma unroll
        for (int off = 1; off < 64; off <<= 1) dot += __shfl_xor(dot, off, 64);
        p = logf(srow[row]) - dot * 0.69314718f;
    }
    if (lane == 0) { pr[row] = p; vf[row] = valid ? 1.0f : 0.0f; }
}

// K6: deterministic fixed-tree reduction -> scalar loss.
__global__ void kfinal(const float* __restrict__ pr, const float* __restrict__ vf,
                       float* __restrict__ out) {
    __shared__ float ls[1024];
    __shared__ float lc[1024];
    int t = threadIdx.x;
    float sv = 0.0f, cv = 0.0f;
#pragma unroll
    for (int k = 0; k < 8; k++) { sv += pr[t * 8 + k]; cv += vf[t * 8 + k]; }
    ls[t] = sv; lc[t] = cv;
    __syncthreads();
    for (int off = 512; off > 0; off >>= 1) {
        if (t < off) { ls[t] += ls[t + off]; lc[t] += lc[t + off]; }
        __syncthreads();
    }
    if (t == 0) out[0] = (lc[0] > 0.0f) ? (ls[0] / lc[0]) : 0.0f;
}

extern "C" void kernel_launch(void* const* d_in, const int* in_sizes, int n_in,
                              void* d_out, int out_size, void* d_ws, size_t ws_size,
                              hipStream_t stream) {
    const float* emb = (const float*)d_in[0];
    const float* th  = (const float*)d_in[1];
    float* out = (float*)d_out;
    char* ws = (char*)d_ws;

    unsigned char* e     = (unsigned char*)(ws);              // 4 MB fp8 [N][D]
    float4*   th4        = (float4*)(ws + 8388608);
    float*    srow       = (float*)(ws + 8519680);
    unsigned* jminr      = (unsigned*)(ws + 8552448);
    unsigned* negr       = (unsigned*)(ws + 8585216);
    float*    pr         = (float*)(ws + 8617984);
    float*    vf         = (float*)(ws + 8650752);
    unsigned* d2mb       = (unsigned*)(ws + 8683520);

    knorm<<<N / 4, 256, 0, stream>>>(emb, e, srow, jminr, negr, d2mb);
    kth<<<256, 256, 0, stream>>>(th, th4, d2mb);
    kmain<<<2080, 256, 0, stream>>>(e, th4, d2mb, srow, jminr, negr);
    krow<<<N / 4, 256, 0, stream>>>(e, srow, jminr, negr, pr, vf);
    kfinal<<<1, 1024, 0, stream>>>(pr, vf, out);
}

// Round 23
// 110.904 us; speedup vs baseline: 1.0153x; 1.0153x over previous
//
#include <hip/hip_runtime.h>

#define N 8192
#define D 512

typedef __attribute__((ext_vector_type(4))) float f32x4;
typedef __attribute__((ext_vector_type(2))) long long2v;

typedef const __attribute__((address_space(1))) unsigned int* gas_t;
typedef __attribute__((address_space(3))) unsigned int* las_t;

static __device__ __forceinline__ void gl_lds16(const void* g, char* l) {
    __builtin_amdgcn_global_load_lds((gas_t)g, (las_t)l, 16, 0, 0);
}
// triangle cumulative for the 64x64 grid of 128-wide tiles: row r owns (64-r) tiles
static __device__ __forceinline__ int tri_cum(int r) { return r * (129 - r) / 2; }

// OCP e4m3 encode (RNE, saturate 448; our inputs are <=~0.7 so never saturate)
static __device__ __forceinline__ unsigned f2fp8(float f) {
    unsigned u = __float_as_uint(f);
    unsigned sgn = (u >> 24) & 0x80u;
    unsigned a = u & 0x7FFFFFFFu;
    if (a >= 0x3C800000u) {                               // >= 2^-6: normal
        unsigned t = a + 0x7FFFFu + ((a >> 20) & 1u);     // RNE to 3-bit mantissa
        unsigned code = (((t >> 23) - 120u) << 3) | ((t >> 20) & 7u);
        if (code > 0x7Eu) code = 0x7Eu;                   // clamp to 448
        return sgn | code;
    }
    float af = __uint_as_float(a);
    unsigned m = (unsigned)(af * 512.0f + 0.5f);          // subnormal: m * 2^-9
    return sgn | (m > 8u ? 8u : m);                       // m==8 -> min normal
}
// OCP e4m3 decode (exact)
static __device__ __forceinline__ float fp82f(unsigned c) {
    unsigned e = (c >> 3) & 15u, m = c & 7u;
    float v = (e == 0u) ? (float)m * 0.001953125f
                        : __uint_as_float(((e + 120u) << 23) | (m << 20));
    return (c & 0x80u) ? -v : v;
}

// K1 (runs FIRST): row-normalize embeddings -> fp8 e4m3 e[N][D], PRE-SCALED by
// sqrt(10*log2(e)); 64B K-chunks stored with 8B units permuted [0,4,1,5,2,6,3,7]
// (one 16B granule = both K-half fragments -> conflict-free b128 in kmain).
// Also inits srow/jminrow/negrow for its 4 rows and zeroes d2mb.
__global__ void knorm(const float* __restrict__ emb, unsigned char* __restrict__ e,
                      float* __restrict__ srow, unsigned* __restrict__ jminrow,
                      unsigned* __restrict__ negrow, unsigned* __restrict__ d2mb) {
    int w    = threadIdx.x >> 6;
    int row  = blockIdx.x * 4 + w;
    int lane = threadIdx.x & 63;
    const float4* src = (const float4*)(emb + (size_t)row * D);
    float4 v0 = src[lane * 2];
    float4 v1 = src[lane * 2 + 1];
    float ss = v0.x*v0.x + v0.y*v0.y + v0.z*v0.z + v0.w*v0.w
             + v1.x*v1.x + v1.y*v1.y + v1.z*v1.z + v1.w*v1.w;
#pragma unroll
    for (int off = 1; off < 64; off <<= 1) ss += __shfl_xor(ss, off, 64);
    // 3.7982826^2 = 14.42695 = 10*log2(e): acc becomes exp2 argument directly
    float inv = 3.7982826f / fmaxf(sqrtf(ss), 1e-12f);
    unsigned c0 = f2fp8(v0.x * inv), c1 = f2fp8(v0.y * inv);
    unsigned c2 = f2fp8(v0.z * inv), c3 = f2fp8(v0.w * inv);
    unsigned c4 = f2fp8(v1.x * inv), c5 = f2fp8(v1.y * inv);
    unsigned c6 = f2fp8(v1.z * inv), c7 = f2fp8(v1.w * inv);
    uint2 pk;
    pk.x = c0 | (c1 << 8) | (c2 << 16) | (c3 << 24);
    pk.y = c4 | (c5 << 8) | (c6 << 16) | (c7 << 24);
    {   // permuted store: lane covers K [lane*8, lane*8+8) = chunk c, unit u
        int c = lane >> 3, u = lane & 7;
        int off8 = c * 64 + ((u < 4) ? u * 16 : (u - 4) * 16 + 8);
        *(uint2*)(e + (size_t)row * D + off8) = pk;
    }
    if (lane == 0) {
        srow[row] = 0.0f;
        jminrow[row] = 0xFFFFFFFFu;
        negrow[row] = 0u;
    }
    if (blockIdx.x == 0 && threadIdx.x == 0) *d2mb = 0u;
}

// K2: pack thetas -> float4 (x,y,z,|t|^2) AND global theta-d2max from RAW th
// (no dependency on th4; d2mb zeroed by knorm which runs first).
__global__ void kth(const float* __restrict__ th, float4* __restrict__ th4,
                    unsigned* __restrict__ d2mb) {
    int tid = threadIdx.x, bid = blockIdx.x;
    if (bid < 32) {
        int i = bid * 256 + tid;
        float x = th[3 * i], y = th[3 * i + 1], z = th[3 * i + 2];
        float4 v; v.x = x; v.y = y; v.z = z; v.w = x * x + y * y + z * z;
        th4[i] = v;
    }
    int w = tid >> 6, lane = tid & 63;
    int widx = bid * 4 + w;             // 0..1023
    int q0 = widx * 4;
    int m0 = N - 4 - q0;
    float4 A[4], B[4];
#pragma unroll
    for (int k = 0; k < 4; k++) {
        float x = th[3 * (q0 + k)], y = th[3 * (q0 + k) + 1], z = th[3 * (q0 + k) + 2];
        A[k].x = x; A[k].y = y; A[k].z = z; A[k].w = x * x + y * y + z * z;
        x = th[3 * (m0 + k)]; y = th[3 * (m0 + k) + 1]; z = th[3 * (m0 + k) + 2];
        B[k].x = x; B[k].y = y; B[k].z = z; B[k].w = x * x + y * y + z * z;
    }
    float m = 0.0f;
    for (int j = q0 + 1 + lane; j < N; j += 64) {
        float x = th[3 * j], y = th[3 * j + 1], z = th[3 * j + 2];
        float tw = x * x + y * y + z * z;
        float d;
        d = A[0].w + tw - 2.0f * (A[0].x*x + A[0].y*y + A[0].z*z); m = fmaxf(m, d);
        d = A[1].w + tw - 2.0f * (A[1].x*x + A[1].y*y + A[1].z*z); m = fmaxf(m, d);
        d = A[2].w + tw - 2.0f * (A[2].x*x + A[2].y*y + A[2].z*z); m = fmaxf(m, d);
        d = A[3].w + tw - 2.0f * (A[3].x*x + A[3].y*y + A[3].z*z); m = fmaxf(m, d);
    }
    for (int j = m0 + 1 + lane; j < N; j += 64) {
        float x = th[3 * j], y = th[3 * j + 1], z = th[3 * j + 2];
        float tw = x * x + y * y + z * z;
        float d;
        d = B[0].w + tw - 2.0f * (B[0].x*x + B[0].y*y + B[0].z*z); m = fmaxf(m, d);
        d = B[1].w + tw - 2.0f * (B[1].x*x + B[1].y*y + B[1].z*z); m = fmaxf(m, d);
        d = B[2].w + tw - 2.0f * (B[2].x*x + B[2].y*y + B[2].z*z); m = fmaxf(m, d);
        d = B[3].w + tw - 2.0f * (B[3].x*x + B[3].y*y + B[3].z*z); m = fmaxf(m, d);
    }
#pragma unroll
    for (int off = 1; off < 64; off <<= 1) m = fmaxf(m, __shfl_xor(m, off, 64));
    __shared__ float red[4];
    if (lane == 0) red[w] = m;
    __syncthreads();
    if (tid == 0) {
        m = fmaxf(fmaxf(red[0], red[1]), fmaxf(red[2], red[3]));
        atomicMax(d2mb, __float_as_uint(m));
    }
}

// K4: symmetric fused GEMM, fp8 e4m3, 128x128 tile over the 64x64 triangle grid
// (2080 blocks), 256 threads = 4 waves (2Mx2N, 64x64/wave, acc 4x4). BK=64,
// THREE 16KB tile-buffers (48 KB LDS): stage(T+2) issued right after the T-barrier,
// per-step wait is a COUNTED vmcnt(4) (stage T+1 stays in flight across the
// barrier) — no mid-loop drain to 0. Fragment reads: single conflict-free
// ds_read_b128 per fragment (unit-permuted global layout). Epilogue = r12's.
// [Session best: kmain ~62.7 us, total ~110.8 us — r19 configuration, final.]
__global__ __launch_bounds__(256) void kmain(
    const unsigned char* __restrict__ e, const float4* __restrict__ th4,
    const unsigned* __restrict__ d2mb, float* __restrict__ srow,
    unsigned* __restrict__ jminrow, unsigned* __restrict__ negrow) {
    __shared__ __align__(16) char smem[49152];   // 3 bufs x (A 8K + B 8K)

    const int tid  = threadIdx.x;
    const int lane = tid & 63;
    const int w    = tid >> 6;        // 0..3
    const int wr   = w >> 1;          // 0..1 (M 64-half)
    const int wc   = w & 1;           // 0..1 (N 64-half)

    // XCD-aware bijective swizzle: 2080 = 8 XCDs x 260; triangle decode (64 rows)
    const int bid = (int)blockIdx.x;
    const int swz = (bid & 7) * 260 + (bid >> 3);
    int rb = (int)((129.0f - sqrtf(16641.0f - 8.0f * (float)swz)) * 0.5f);
    rb = rb < 0 ? 0 : (rb > 63 ? 63 : rb);
    while (tri_cum(rb + 1) <= swz) rb++;
    while (tri_cum(rb) > swz) rb--;
    const int cb = rb + (swz - tri_cum(rb));
    const bool isdiag = (rb == cb);
    const int r0 = rb * 128, c0 = cb * 128;

    // staging (BK=64 fp8): per buf, A = 128 rows x 64 B at [0], B at [8192].
    // thread t pass p: row = (t>>2) + 64p, 16B-granule = t&3; LDS dest linear
    // t*16 (+4096/pass). global granule pre-swizzled:
    // LDS[row][g] = global(row, g ^ ((row>>1)&3)).
    const int ssw = (((tid & 3) ^ ((tid >> 3) & 3)) << 4);   // byte offset
    const unsigned char* pA0 = e + (size_t)(r0 + (tid >> 2)) * D + ssw;
    const unsigned char* pA1 = pA0 + (size_t)64 * D;
    const unsigned char* pB0 = e + (size_t)(c0 + (tid >> 2)) * D + ssw;
    const unsigned char* pB1 = pB0 + (size_t)64 * D;

    const int fr = lane & 15;
    const int fq = lane >> 4;
    // one b128 per fragment: granule fq ^ ((fr>>1)&3); contains both ks halves
    const int kslot = (fq ^ ((fr >> 1) & 3)) << 4;

    f32x4 acc[4][4];
#pragma unroll
    for (int mt = 0; mt < 4; mt++)
#pragma unroll
        for (int nt = 0; nt < 4; nt++) acc[mt][nt] = (f32x4){0.f, 0.f, 0.f, 0.f};

#define STAGE(T, BUF) { \
    const int k0_ = (T) * 64; char* d_ = smem + (BUF) * 16384;   \
    gl_lds16(pA0 + k0_, d_ + tid * 16);                          \
    gl_lds16(pA1 + k0_, d_ + 4096 + tid * 16);                   \
    gl_lds16(pB0 + k0_, d_ + 8192 + tid * 16);                   \
    gl_lds16(pB1 + k0_, d_ + 12288 + tid * 16); }

#define COMPUTE(BUF) { \
    const char* cA_ = smem + (BUF) * 16384;                      \
    const char* cB_ = cA_ + 8192;                                \
    long2v a_[4], b_[4];                                         \
    _Pragma("unroll")                                            \
    for (int mt = 0; mt < 4; mt++)                               \
        a_[mt] = *(const long2v*)(cA_ + (wr * 64 + mt * 16 + fr) * 64 + kslot); \
    _Pragma("unroll")                                            \
    for (int nt = 0; nt < 4; nt++)                               \
        b_[nt] = *(const long2v*)(cB_ + (wc * 64 + nt * 16 + fr) * 64 + kslot); \
    _Pragma("unroll")                                            \
    for (int mt = 0; mt < 4; mt++)                               \
    _Pragma("unroll")                                            \
    for (int nt = 0; nt < 4; nt++) {                             \
        acc[mt][nt] = __builtin_amdgcn_mfma_f32_16x16x32_fp8_fp8( \
            a_[mt][0], b_[nt][0], acc[mt][nt], 0, 0, 0);         \
        acc[mt][nt] = __builtin_amdgcn_mfma_f32_16x16x32_fp8_fp8( \
            a_[mt][1], b_[nt][1], acc[mt][nt], 0, 0, 0);         \
    } }

// step: counted wait (stage T landed; T+1 in flight) -> barrier -> issue T+2 -> compute T
#define KST(WAITN, SBUF, DOSTAGE, ST, CBUF)                       \
    asm volatile("s_waitcnt vmcnt(" #WAITN ")" ::: "memory");     \
    __builtin_amdgcn_s_barrier();                                 \
    __builtin_amdgcn_sched_barrier(0);                            \
    if (DOSTAGE) STAGE(ST, SBUF)                                  \
    COMPUTE(CBUF)

    STAGE(0, 0)
    STAGE(1, 1)
    KST(4, 2, 1, 2, 0)   // T=0
    KST(4, 0, 1, 3, 1)   // T=1
    KST(4, 1, 1, 4, 2)   // T=2
    KST(4, 2, 1, 5, 0)   // T=3
    KST(4, 0, 1, 6, 1)   // T=4
    KST(4, 1, 1, 7, 2)   // T=5
    KST(4, 0, 0, 0, 0)   // T=6 (no stage)
    KST(0, 0, 0, 0, 1)   // T=7 (final drain)
#undef KST
#undef COMPUTE
#undef STAGE
    __syncthreads();   // all compute done; LDS reused by the reduction below

    // ---- fused epilogue (acc is the exp2 argument directly) ----
    const float dmax = sqrtf(__uint_as_float(*d2mb)) + 1e-8f;
    const float p2 = 0.0225f * dmax * dmax;   // (0.15*dmax)^2
    const float n2 = 0.1225f * dmax * dmax;   // (0.35*dmax)^2

    const int j0 = c0 + wc * 64 + fr;
    float4 thj[4];
#pragma unroll
    for (int nt = 0; nt < 4; nt++) thj[nt] = th4[j0 + nt * 16];

    float*    lds_rs = (float*)smem;              // [2][128] row sums (by wc)
    unsigned* lds_rj = (unsigned*)(smem + 1024);
    unsigned* lds_rn = (unsigned*)(smem + 2048);
    float*    lds_cs = (float*)(smem + 3072);     // [2][128] col sums (by wr)
    unsigned* lds_cj = (unsigned*)(smem + 4096);
    unsigned* lds_cn = (unsigned*)(smem + 5120);

    float    csum[4]; unsigned cjm[4], cng[4];
#pragma unroll
    for (int nt = 0; nt < 4; nt++) { csum[nt] = 0.0f; cjm[nt] = 0xFFFFFFFFu; cng[nt] = 0u; }

    const int i0 = r0 + wr * 64 + fq * 4;
#pragma unroll
    for (int mt = 0; mt < 4; mt++) {
#pragma unroll
        for (int rr = 0; rr < 4; rr++) {
            const int i = i0 + mt * 16 + rr;
            const float4 ti = th4[i];
            float sv = 0.0f; unsigned jv = 0xFFFFFFFFu, nv = 0u;
#pragma unroll
            for (int nt = 0; nt < 4; nt++) {
                const int j = j0 + nt * 16;
                const float4 tj = thj[nt];
                float dot = ti.x * tj.x + ti.y * tj.y + ti.z * tj.z;
                float d2 = fmaf(-2.0f, dot, ti.w + tj.w);
                bool pos = isdiag ? ((d2 < p2) && (j != i)) : (d2 < p2);
                bool neg = (d2 > n2);
                float c = (pos || neg) ? exp2f(acc[mt][nt][rr]) : 0.0f;
                sv += c;
                if (neg) nv = 1u;
                if (pos) jv = min(jv, (unsigned)j);
                if (!isdiag) {
                    csum[nt] += c;
                    if (neg) cng[nt] = 1u;
                    if (pos) cjm[nt] = min(cjm[nt], (unsigned)i);
                }
            }
            // row-side reduce across the 16 fr-lanes
#pragma unroll
            for (int off = 1; off < 16; off <<= 1) {
                sv += __shfl_xor(sv, off, 64);
                jv = min(jv, (unsigned)__shfl_xor((int)jv, off, 64));
                nv |= (unsigned)__shfl_xor((int)nv, off, 64);
            }
            if (fr == 0) {
                const int rl = wr * 64 + mt * 16 + fq * 4 + rr;
                lds_rs[wc * 128 + rl] = sv;
                lds_rj[wc * 128 + rl] = jv;
                lds_rn[wc * 128 + rl] = nv;
            }
        }
    }

    // column-side reduce across the 4 fq groups (lane^16, lane^32)
    if (!isdiag) {
#pragma unroll
        for (int nt = 0; nt < 4; nt++) {
            float sv = csum[nt]; unsigned jv = cjm[nt], nv = cng[nt];
#pragma unroll
            for (int off = 16; off < 64; off <<= 1) {
                sv += __shfl_xor(sv, off, 64);
                jv = min(jv, (unsigned)__shfl_xor((int)jv, off, 64));
                nv |= (unsigned)__shfl_xor((int)nv, off, 64);
            }
            if (fq == 0) {
                const int cl = wc * 64 + nt * 16 + fr;
                lds_cs[wr * 128 + cl] = sv;
                lds_cj[wr * 128 + cl] = jv;
                lds_cn[wr * 128 + cl] = nv;
            }
        }
    }
    __syncthreads();
    if (tid < 128) {
        float    sv = lds_rs[tid] + lds_rs[128 + tid];
        unsigned jv = min(lds_rj[tid], lds_rj[128 + tid]);
        unsigned nv = lds_rn[tid] | lds_rn[128 + tid];
        atomicAdd(&srow[r0 + tid], sv);
        atomicMin(&jminrow[r0 + tid], jv);
        atomicOr(&negrow[r0 + tid], nv);
        if (!isdiag) {
            float    cv = lds_cs[tid] + lds_cs[128 + tid];
            unsigned cj = min(lds_cj[tid], lds_cj[128 + tid]);
            unsigned cn = lds_cn[tid] | lds_cn[128 + tid];
            atomicAdd(&srow[c0 + tid], cv);
            atomicMin(&jminrow[c0 + tid], cj);
            atomicOr(&negrow[c0 + tid], cn);
        }
    }
}

// K5: per-row finalize. e is fp8 (unit-permuted rows; dot is permutation-invariant),
// pre-scaled: sim = dot_scaled * ln2.
__global__ void krow(const unsigned char* __restrict__ e, const float* __restrict__ srow,
                     const unsigned* __restrict__ jminrow, const unsigned* __restrict__ negrow,
                     float* __restrict__ pr, float* __restrict__ vf) {
    int row  = blockIdx.x * 4 + (threadIdx.x >> 6);
    int lane = threadIdx.x & 63;
    unsigned jmv = jminrow[row];
    bool valid = (jmv != 0xFFFFFFFFu) && (negrow[row] != 0u);
    float p = 0.0f;
    if (valid) {
        const uint2* a = (const uint2*)(e + (size_t)row * D);
        const uint2* b = (const uint2*)(e + (size_t)jmv * D);
        uint2 va = a[lane], vb = b[lane];
        float dot = 0.0f;
#pragma unroll
        for (int k = 0; k < 4; k++)
            dot += fp82f((va.x >> (8 * k)) & 0xFFu) * fp82f((vb.x >> (8 * k)) & 0xFFu);
#pragma unroll
        for (int k = 0; k < 4; k++)
            dot += fp82f((va.y >> (8 * k)) & 0xFFu) * fp82f((vb.y >> (8 * k)) & 0xFFu);
#pragma unroll
        for (int off = 1; off < 64; off <<= 1) dot += __shfl_xor(dot, off, 64);
        p = logf(srow[row]) - dot * 0.69314718f;
    }
    if (lane == 0) { pr[row] = p; vf[row] = valid ? 1.0f : 0.0f; }
}

// K6: deterministic fixed-tree reduction -> scalar loss.
__global__ void kfinal(const float* __restrict__ pr, const float* __restrict__ vf,
                       float* __restrict__ out) {
    __shared__ float ls[1024];
    __shared__ float lc[1024];
    int t = threadIdx.x;
    float sv = 0.0f, cv = 0.0f;
#pragma unroll
    for (int k = 0; k < 8; k++) { sv += pr[t * 8 + k]; cv += vf[t * 8 + k]; }
    ls[t] = sv; lc[t] = cv;
    __syncthreads();
    for (int off = 512; off > 0; off >>= 1) {
        if (t < off) { ls[t] += ls[t + off]; lc[t] += lc[t + off]; }
        __syncthreads();
    }
    if (t == 0) out[0] = (lc[0] > 0.0f) ? (ls[0] / lc[0]) : 0.0f;
}

extern "C" void kernel_launch(void* const* d_in, const int* in_sizes, int n_in,
                              void* d_out, int out_size, void* d_ws, size_t ws_size,
                              hipStream_t stream) {
    const float* emb = (const float*)d_in[0];
    const float* th  = (const float*)d_in[1];
    float* out = (float*)d_out;
    char* ws = (char*)d_ws;

    unsigned char* e     = (unsigned char*)(ws);              // 4 MB fp8 [N][D]
    float4*   th4        = (float4*)(ws + 8388608);
    float*    srow       = (float*)(ws + 8519680);
    unsigned* jminr      = (unsigned*)(ws + 8552448);
    unsigned* negr       = (unsigned*)(ws + 8585216);
    float*    pr         = (float*)(ws + 8617984);
    float*    vf         = (float*)(ws + 8650752);
    unsigned* d2mb       = (unsigned*)(ws + 8683520);

    knorm<<<N / 4, 256, 0, stream>>>(emb, e, srow, jminr, negr, d2mb);
    kth<<<256, 256, 0, stream>>>(th, th4, d2mb);
    kmain<<<2080, 256, 0, stream>>>(e, th4, d2mb, srow, jminr, negr);
    krow<<<N / 4, 256, 0, stream>>>(e, srow, jminr, negr, pr, vf);
    kfinal<<<1, 1024, 0, stream>>>(pr, vf, out);
}